// Round 1
// 353.261 us; speedup vs baseline: 1.9269x; 1.9269x over previous
//
#include <hip/hip_runtime.h>
#include <stdint.h>
#include <math.h>

#define B_ 4
#define S_ 2048
#define D_ 4096
#define O_ 4096
#define E_ 8
#define R_ 32
#define SCALING 2.0f
#define NOISE_EPS 0.01f

typedef unsigned short u16;
typedef short s16x8 __attribute__((ext_vector_type(8)));   // 8 bf16 = 4 VGPRs
typedef float f32x4 __attribute__((ext_vector_type(4)));

__device__ __forceinline__ float b2f(u16 u) {
  union { unsigned int i; float f; } v; v.i = ((unsigned int)u) << 16; return v.f;
}
__device__ __forceinline__ u16 f2b(float f) {
  union { unsigned int i; float f; } v; v.f = f;
  unsigned int i = v.i;
  return (u16)((i + 0x7FFFu + ((i >> 16) & 1u)) >> 16);  // RNE
}

// dtype-adaptive element access: bf=1 -> bf16, bf=0 -> fp32
__device__ __forceinline__ float ld(const void* p, size_t i, int bf) {
  return bf ? b2f(((const u16*)p)[i]) : ((const float*)p)[i];
}

// ---------------------------------------------------------------------------
// Kernel 0: detect dtype of float inputs by inspecting x's bit patterns.
// ---------------------------------------------------------------------------
__global__ void k_detect(const unsigned int* __restrict__ xw, int* __restrict__ flag) {
  __shared__ int cnt;
  if (threadIdx.x == 0) cnt = 0;
  __syncthreads();
  unsigned int w = xw[threadIdx.x];
  unsigned int e = (w >> 7) & 0xFFu;
  if (e >= 90u && e <= 140u) atomicAdd(&cnt, 1);
  __syncthreads();
  if (threadIdx.x == 0) *flag = (cnt > 48) ? 1 : 0;
}

// ---------------------------------------------------------------------------
// Kernel 1: clean/noise logits. One block per (b,e).
// ---------------------------------------------------------------------------
__global__ __launch_bounds__(256) void k_logits(
    const void* __restrict__ x, const int* __restrict__ eof,
    const void* __restrict__ route_w, const void* __restrict__ noise_w,
    const int* __restrict__ flag, float* __restrict__ wsf) {
  int bf = *flag;
  int be = blockIdx.x;            // 0..31
  int b = be >> 3, e = be & 7;
  size_t xoff = ((size_t)b * S_ + (size_t)eof[b]) * D_;
  size_t woff = (size_t)e * D_;
  float ac = 0.f, an = 0.f;
  for (int d = threadIdx.x; d < D_; d += 256) {
    float xv = ld(x, xoff + d, bf);
    ac += xv * ld(route_w, woff + d, bf);
    an += xv * ld(noise_w, woff + d, bf);
  }
  __shared__ float rc[256], rn[256];
  rc[threadIdx.x] = ac; rn[threadIdx.x] = an;
  __syncthreads();
  for (int s = 128; s > 0; s >>= 1) {
    if (threadIdx.x < (unsigned)s) {
      rc[threadIdx.x] += rc[threadIdx.x + s];
      rn[threadIdx.x] += rn[threadIdx.x + s];
    }
    __syncthreads();
  }
  if (threadIdx.x == 0) { wsf[16 + be] = rc[0]; wsf[48 + be] = rn[0]; }
}

// ---------------------------------------------------------------------------
// Kernel 2: noisy top-2 softmax gates.
// ---------------------------------------------------------------------------
__global__ void k_gates(const void* __restrict__ noise, const int* __restrict__ flag,
                        float* __restrict__ wsf) {
  int bf = *flag;
  int b = threadIdx.x;
  if (b >= B_) return;
  float lg[E_];
  for (int e = 0; e < E_; e++) {
    float c = wsf[16 + b * 8 + e];
    float n = wsf[48 + b * 8 + e];
    float sp = (n > 20.f) ? n : log1pf(expf(n));   // softplus
    lg[e] = c + ld(noise, b * 8 + e, bf) * (sp + NOISE_EPS);
  }
  int i1 = 0; float v1 = lg[0];
  for (int e = 1; e < E_; e++) if (lg[e] > v1) { v1 = lg[e]; i1 = e; }
  int i2 = -1; float v2 = -3.0e38f;
  for (int e = 0; e < E_; e++) if (e != i1 && lg[e] > v2) { v2 = lg[e]; i2 = e; }
  float t = expf(v2 - v1);              // v2 <= v1, stable
  float g1 = 1.f / (1.f + t);
  float g2 = t / (1.f + t);
  for (int e = 0; e < E_; e++) wsf[80 + b * 8 + e] = 0.f;
  wsf[80 + b * 8 + i1] = g1;
  wsf[80 + b * 8 + i2] = g2;
}

// ---------------------------------------------------------------------------
// Kernel 3: Wc[b,o,r] = SCALING * sum_e gates[b,e] * B_w[e,o,r]   (fp32 out)
// vectorized x4
// ---------------------------------------------------------------------------
__global__ __launch_bounds__(256) void k_wc(
    const void* __restrict__ Bw, const int* __restrict__ flag,
    const float* __restrict__ gates, float* __restrict__ Wc) {
  int bf = *flag;
  int idx = blockIdx.x * 256 + threadIdx.x;     // 0 .. 131071 (groups of 4)
  int b = idx >> 15;
  int u = idx & 32767;                          // 4-elem group within this b
  float g[E_];
#pragma unroll
  for (int e = 0; e < E_; e++) g[e] = gates[b * 8 + e];
  f32x4 acc = {0.f, 0.f, 0.f, 0.f};
  if (bf) {
#pragma unroll
    for (int e = 0; e < E_; e++) {
      ushort4 v = ((const ushort4*)Bw)[(size_t)e * 32768 + u];
      acc[0] += g[e] * b2f(v.x);
      acc[1] += g[e] * b2f(v.y);
      acc[2] += g[e] * b2f(v.z);
      acc[3] += g[e] * b2f(v.w);
    }
  } else {
#pragma unroll
    for (int e = 0; e < E_; e++) {
      f32x4 v = ((const f32x4*)Bw)[(size_t)e * 32768 + u];
      acc += g[e] * v;
    }
  }
  ((f32x4*)Wc)[idx] = acc * SCALING;
}

// ---------------------------------------------------------------------------
// Kernel 4a (bf16 path): shared[row, r] = sum_d x[row, d] * A_w[r, d] via MFMA.
// One wave = 16 rows x 32 cols. Fragments load straight from global (x has
// zero reuse across waves; A_w is 256 KB and L2-resident).
// Layout (verified m89/m97 family): A-op lane l -> row=l&15, k=(l>>4)*8+j;
// B-op lane l -> col(r)=l&15, same k.  C/D: col=lane&15, row=(lane>>4)*4+reg.
// ---------------------------------------------------------------------------
__global__ __launch_bounds__(128) void k_shared_mfma(
    const void* __restrict__ xv, const void* __restrict__ Awv,
    const int* __restrict__ flag, float* __restrict__ sh_out) {
  if (!*flag) return;                 // fp32 inputs -> fallback kernel handles
  const u16* x  = (const u16*)xv;
  const u16* Aw = (const u16*)Awv;
  int lane = threadIdx.x & 63;
  int wave = threadIdx.x >> 6;        // 0..1
  int m = lane & 15, kg = lane >> 4;  // fragment row / k-group
  int row0 = (blockIdx.x * 2 + wave) * 16;
  const u16* xp  = x  + (size_t)(row0 + m) * D_ + kg * 8;
  const u16* a0p = Aw + (size_t)m * D_ + kg * 8;          // r = 0..15
  const u16* a1p = Aw + (size_t)(m + 16) * D_ + kg * 8;   // r = 16..31
  f32x4 acc0 = {0.f, 0.f, 0.f, 0.f};
  f32x4 acc1 = {0.f, 0.f, 0.f, 0.f};
#pragma unroll 4
  for (int k0 = 0; k0 < D_; k0 += 32) {
    s16x8 a  = *(const s16x8*)(xp + k0);
    s16x8 b0 = *(const s16x8*)(a0p + k0);
    s16x8 b1 = *(const s16x8*)(a1p + k0);
    acc0 = __builtin_amdgcn_mfma_f32_16x16x32_bf16(a, b0, acc0, 0, 0, 0);
    acc1 = __builtin_amdgcn_mfma_f32_16x16x32_bf16(a, b1, acc1, 0, 0, 0);
  }
  int col = lane & 15;
  int rbase = (lane >> 4) * 4;
  float* outp = sh_out + (size_t)row0 * R_;
#pragma unroll
  for (int j = 0; j < 4; j++) {
    outp[(size_t)(rbase + j) * R_ + col]      = acc0[j];
    outp[(size_t)(rbase + j) * R_ + col + 16] = acc1[j];
  }
}

// ---------------------------------------------------------------------------
// Kernel 4b (fp32 fallback): previous LDS-tiled kernel, runs only if bf==0.
// ---------------------------------------------------------------------------
#define BK 256
__global__ __launch_bounds__(256) void k_shared_f32(
    const void* __restrict__ x, const void* __restrict__ Aw,
    const int* __restrict__ flag, float* __restrict__ sh_out) {
  if (*flag) return;                  // bf16 inputs -> MFMA kernel handles
  __shared__ float xs[16][BK + 1];
  __shared__ float as[32][BK + 1];
  int tid = threadIdx.x;
  int row0 = blockIdx.x * 16;
  int rrow = tid >> 4;     // 0..15
  int rr = tid & 15;       // 0..15
  float acc0 = 0.f, acc1 = 0.f;
  for (int kc = 0; kc < D_; kc += BK) {
#pragma unroll
    for (int it = 0; it < 16; it++)
      xs[it][tid] = ((const float*)x)[(size_t)(row0 + it) * D_ + kc + tid];
#pragma unroll
    for (int it = 0; it < 32; it++)
      as[it][tid] = ((const float*)Aw)[(size_t)it * D_ + kc + tid];
    __syncthreads();
#pragma unroll 8
    for (int k = 0; k < BK; k++) {
      float xv = xs[rrow][k];
      acc0 += xv * as[rr][k];
      acc1 += xv * as[rr + 16][k];
    }
    __syncthreads();
  }
  sh_out[(size_t)(row0 + rrow) * R_ + rr] = acc0;
  sh_out[(size_t)(row0 + rrow) * R_ + rr + 16] = acc1;
}

// ---------------------------------------------------------------------------
// Kernel 5: out[row, o] = sum_r shared[row, r] * Wc[b, o, r]
// Block tile: 32 rows x 256 cols. Thread tile: 8 rows x 4 cols (outer product,
// 32 fp32 accumulators). Wc staged TRANSPOSED in LDS so the o-dim is the
// vector dim; sh rows are wave-uniform broadcasts.
// ---------------------------------------------------------------------------
__global__ __launch_bounds__(256) void k_out(
    const float* __restrict__ shw, const float* __restrict__ Wc,
    const int* __restrict__ flag, void* __restrict__ out) {
  __shared__ float WcT[32][260];   // [r][o-o0], row stride 1040 B (16B-aligned)
  __shared__ float shs[32][36];    // [row-row0][r]
  int bf = *flag;
  int t = threadIdx.x;
  int o0   = (blockIdx.x & 15) * 256;
  int row0 = (blockIdx.x >> 4) * 32;
  int b = row0 >> 11;
  // stage Wc^T: thread t owns column o0+t
  {
    const f32x4* wp = (const f32x4*)(Wc + ((size_t)b * O_ + (o0 + t)) * R_);
#pragma unroll
    for (int j = 0; j < 8; j++) {
      f32x4 f = wp[j];
      WcT[j * 4 + 0][t] = f[0];
      WcT[j * 4 + 1][t] = f[1];
      WcT[j * 4 + 2][t] = f[2];
      WcT[j * 4 + 3][t] = f[3];
    }
  }
  // stage sh: 8 threads per row
  {
    int row = t >> 3, rc = (t & 7) * 4;
    *(f32x4*)&shs[row][rc] = *(const f32x4*)(shw + (size_t)(row0 + row) * R_ + rc);
  }
  __syncthreads();
  int o4 = (t & 63) * 4;           // col offset within tile
  int rbase = (t >> 6) * 8;        // row group within tile
  f32x4 acc[8];
#pragma unroll
  for (int i = 0; i < 8; i++) acc[i] = (f32x4){0.f, 0.f, 0.f, 0.f};
#pragma unroll 2
  for (int rc = 0; rc < R_; rc += 4) {
    f32x4 w0 = *(const f32x4*)&WcT[rc + 0][o4];
    f32x4 w1 = *(const f32x4*)&WcT[rc + 1][o4];
    f32x4 w2 = *(const f32x4*)&WcT[rc + 2][o4];
    f32x4 w3 = *(const f32x4*)&WcT[rc + 3][o4];
#pragma unroll
    for (int i = 0; i < 8; i++) {
      f32x4 a = *(const f32x4*)&shs[rbase + i][rc];
      acc[i] += a[0] * w0 + a[1] * w1 + a[2] * w2 + a[3] * w3;
    }
  }
#pragma unroll
  for (int i = 0; i < 8; i++) {
    size_t off = (size_t)(row0 + rbase + i) * O_ + o0 + o4;
    if (bf) {
      ushort4 v;
      v.x = f2b(acc[i][0]); v.y = f2b(acc[i][1]);
      v.z = f2b(acc[i][2]); v.w = f2b(acc[i][3]);
      *(ushort4*)((u16*)out + off) = v;
    } else {
      *(f32x4*)((float*)out + off) = acc[i];
    }
  }
}

// ---------------------------------------------------------------------------
extern "C" void kernel_launch(void* const* d_in, const int* in_sizes, int n_in,
                              void* d_out, int out_size, void* d_ws, size_t ws_size,
                              hipStream_t stream) {
  const void* x       = d_in[0];                 // [4,2048,4096] f32 or bf16
  const int*  eof     = (const int*)d_in[1];     // [4]
  const void* noise   = d_in[2];                 // [4,8]
  const void* Aw      = d_in[3];                 // [32,4096]
  const void* Bw      = d_in[4];                 // [8,4096,32]
  const void* route_w = d_in[5];                 // [8,4096]
  const void* noise_w = d_in[6];                 // [8,4096]
  float* wsf = (float*)d_ws;
  int* flag = (int*)wsf;                         // wsf[0]
  // ws layout (floats): [0] flag | [16,48) clean | [48,80) noise logits |
  // [80,112) gates | [112, +524288) Wc | then 262144 floats of shared
  float* gates = wsf + 80;
  float* Wc    = wsf + 112;
  float* shw   = wsf + 112 + (size_t)B_ * O_ * R_;

  k_detect<<<1, 64, 0, stream>>>((const unsigned int*)x, flag);
  k_logits<<<B_ * E_, 256, 0, stream>>>(x, eof, route_w, noise_w, flag, wsf);
  k_gates<<<1, 64, 0, stream>>>(noise, flag, wsf);
  k_wc<<<(B_ * O_ * R_ / 4) / 256, 256, 0, stream>>>(Bw, flag, gates, Wc);
  k_shared_mfma<<<(B_ * S_) / 32, 128, 0, stream>>>(x, Aw, flag, shw);
  k_shared_f32<<<(B_ * S_) / 16, 256, 0, stream>>>(x, Aw, flag, shw);
  k_out<<<((B_ * S_) / 32) * (O_ / 256), 256, 0, stream>>>(shw, Wc, flag, d_out);
}